// Round 3
// baseline (588.594 us; speedup 1.0000x reference)
//
#include <hip/hip_runtime.h>
#include <cstdint>

// 8-lane-cooperative scheme (fully coalesced): lane i loads float4 #i; one
// element's 32 spike floats span 8 consecutive lanes (4 floats/lane). Each
// lane packs its 4 bits pre-shifted into IEEE MSB-first position; a 3-step
// OR-butterfly on the VALU DPP pipe (no LDS ops, no lgkmcnt) gives every lane
// the full word. All 8 lanes redundantly do the IEEE fp32 multiply; each lane
// unpacks its own 4 output bits -> coalesced float4 store.
//
// Round 3 = Round 2 resubmit (container infra failure, not a kernel fault):
//  - One-shot structure (no loop, no register reuse across iterations).
//  - Each thread owns FOUR element-groups from 4 disjoint coalesced streams
//    (t, t+n4q, t+2n4q, t+3n4q). 8 independent loads into distinct named
//    registers issued up front -> 4x memory-level parallelism per wave vs
//    the 564us baseline.
//  - n4q is a multiple of 8, so the nibble shift sb is shared by all four.

#define OR_DPP(v, ctrl) \
    ((v) | (uint32_t)__builtin_amdgcn_update_dpp(0, (int)(v), (ctrl), 0xF, 0xF, true))

#define DPP_QUAD_XOR1 0xB1        // quad_perm:[1,0,3,2]
#define DPP_QUAD_XOR2 0x4E        // quad_perm:[2,3,0,1]
#define DPP_ROW_HALF_MIRROR 0x141 // lane i -> 7-i within each 8-lane group

__device__ __forceinline__ uint32_t pack4(float4 v, int sb) {
    return ((v.x > 0.5f ? 8u : 0u) | (v.y > 0.5f ? 4u : 0u) |
            (v.z > 0.5f ? 2u : 0u) | (v.w > 0.5f ? 1u : 0u)) << sb;
}

__device__ __forceinline__ uint32_t butterfly8(uint32_t w) {
    w = OR_DPP(w, DPP_QUAD_XOR1);        // OR across xor-1 pairs
    w = OR_DPP(w, DPP_QUAD_XOR2);        // OR across xor-2 -> 4-lane groups done
    w = OR_DPP(w, DPP_ROW_HALF_MIRROR);  // i -> 7-i merges the two 4-groups
    return w;
}

__device__ __forceinline__ float4 unpack4(uint32_t wp, int sb) {
    float4 o;
    o.x = (float)((wp >> (sb + 3)) & 1u);
    o.y = (float)((wp >> (sb + 2)) & 1u);
    o.z = (float)((wp >> (sb + 1)) & 1u);
    o.w = (float)((wp >> sb) & 1u);
    return o;
}

__global__ __launch_bounds__(256) void spikefp32mul_kernel(
    const float4* __restrict__ A4, const float4* __restrict__ B4,
    float4* __restrict__ O4, int n4q)
{
    int t = blockIdx.x * blockDim.x + threadIdx.x;
    if (t >= n4q) return;

    // Bit j = 4*(t&7)+c is IEEE bit 31-j; nibble base shift. n4q % 8 == 0 so
    // all four streams share the same sb.
    const int sb = 28 - 4 * (t & 7);

    // 8 independent loads, distinct registers -> all in flight together.
    float4 a0 = A4[t];
    float4 b0 = B4[t];
    float4 a1 = A4[t + n4q];
    float4 b1 = B4[t + n4q];
    float4 a2 = A4[t + 2 * n4q];
    float4 b2 = B4[t + 2 * n4q];
    float4 a3 = A4[t + 3 * n4q];
    float4 b3 = B4[t + 3 * n4q];

    uint32_t wa0 = butterfly8(pack4(a0, sb));
    uint32_t wb0 = butterfly8(pack4(b0, sb));
    uint32_t wp0 = __float_as_uint(__uint_as_float(wa0) * __uint_as_float(wb0));
    O4[t] = unpack4(wp0, sb);

    uint32_t wa1 = butterfly8(pack4(a1, sb));
    uint32_t wb1 = butterfly8(pack4(b1, sb));
    uint32_t wp1 = __float_as_uint(__uint_as_float(wa1) * __uint_as_float(wb1));
    O4[t + n4q] = unpack4(wp1, sb);

    uint32_t wa2 = butterfly8(pack4(a2, sb));
    uint32_t wb2 = butterfly8(pack4(b2, sb));
    uint32_t wp2 = __float_as_uint(__uint_as_float(wa2) * __uint_as_float(wb2));
    O4[t + 2 * n4q] = unpack4(wp2, sb);

    uint32_t wa3 = butterfly8(pack4(a3, sb));
    uint32_t wb3 = butterfly8(pack4(b3, sb));
    uint32_t wp3 = __float_as_uint(__uint_as_float(wa3) * __uint_as_float(wb3));
    O4[t + 3 * n4q] = unpack4(wp3, sb);
}

extern "C" void kernel_launch(void* const* d_in, const int* in_sizes, int n_in,
                              void* d_out, int out_size, void* d_ws, size_t ws_size,
                              hipStream_t stream) {
    const float4* A4 = (const float4*)d_in[0];
    const float4* B4 = (const float4*)d_in[1];
    float4* O4 = (float4*)d_out;

    int n4 = in_sizes[0] / 4;   // 16,777,216 float4s (divisible by 4*8)
    int n4q = n4 >> 2;          // 4,194,304 per stream
    const int block = 256;
    int grid = (n4q + block - 1) / block;   // 16384 blocks
    spikefp32mul_kernel<<<grid, block, 0, stream>>>(A4, B4, O4, n4q);
}

// Round 5
// 555.830 us; speedup vs baseline: 1.0589x; 1.0589x over previous
//
#include <hip/hip_runtime.h>
#include <cstdint>

// Round-0 winning structure (1 element-group per thread, fully coalesced,
// DPP OR-butterfly) + non-temporal hints on all three streams.
//
// Round 5 fix: __builtin_nontemporal_load/store reject HIP_vector_type
// (float4 class); use clang native ext_vector_type(4) float instead — same
// dwordx4 access, plus the nt bit.
//
// Why nt: counters show traffic is already minimal (FETCH == A exactly: B is
// ~100% L3-resident from the harness restore; WRITE == O exactly). Pin-level
// this is a pure copy pattern, yet we run at 3.1 TB/s vs the 6.3 TB/s copy
// ceiling. MLP is provably abundant (~46KB/CU in flight vs ~7-16KB needed;
// two MLP-increasing variants both regressed). Remaining suspect: Infinity
// Cache churn — A-misses and O-writes allocate zero-reuse lines, evicting
// the B-resident set. 'nt' keeps A and O from churning L3 while B still hits.
//
// Scheme recap: lane i loads float4 #i; one element's 32 spike floats span 8
// consecutive lanes (4 floats/lane). Each lane packs its 4 bits pre-shifted
// into IEEE MSB-first position; 3-step OR-butterfly on the VALU DPP pipe.
// All 8 lanes redundantly do the IEEE fp32 multiply; each lane unpacks its
// own 4 output bits -> coalesced store.

typedef float vfloat4 __attribute__((ext_vector_type(4)));

#define OR_DPP(v, ctrl) \
    ((v) | (uint32_t)__builtin_amdgcn_update_dpp(0, (int)(v), (ctrl), 0xF, 0xF, true))

#define DPP_QUAD_XOR1 0xB1        // quad_perm:[1,0,3,2]
#define DPP_QUAD_XOR2 0x4E        // quad_perm:[2,3,0,1]
#define DPP_ROW_HALF_MIRROR 0x141 // lane i -> 7-i within each 8-lane group

__global__ __launch_bounds__(256) void spikefp32mul_kernel(
    const vfloat4* __restrict__ A4, const vfloat4* __restrict__ B4,
    vfloat4* __restrict__ O4, int n4)
{
    int g = blockIdx.x * blockDim.x + threadIdx.x;
    if (g >= n4) return;

    vfloat4 a = __builtin_nontemporal_load(&A4[g]);
    vfloat4 b = __builtin_nontemporal_load(&B4[g]);

    // float index f = 4g + c belongs to element g/8, bit j = f%32 = 4*(g&7)+c,
    // which is IEEE bit 31-j. Nibble base shift:
    const int sb = 28 - 4 * (g & 7);

    uint32_t wa = ((a.x > 0.5f ? 8u : 0u) | (a.y > 0.5f ? 4u : 0u) |
                   (a.z > 0.5f ? 2u : 0u) | (a.w > 0.5f ? 1u : 0u)) << sb;
    uint32_t wb = ((b.x > 0.5f ? 8u : 0u) | (b.y > 0.5f ? 4u : 0u) |
                   (b.z > 0.5f ? 2u : 0u) | (b.w > 0.5f ? 1u : 0u)) << sb;

    // OR-butterfly across the 8 lanes of this element group (VALU DPP only).
    wa = OR_DPP(wa, DPP_QUAD_XOR1);
    wb = OR_DPP(wb, DPP_QUAD_XOR1);
    wa = OR_DPP(wa, DPP_QUAD_XOR2);
    wb = OR_DPP(wb, DPP_QUAD_XOR2);
    wa = OR_DPP(wa, DPP_ROW_HALF_MIRROR);
    wb = OR_DPP(wb, DPP_ROW_HALF_MIRROR);

    float p = __uint_as_float(wa) * __uint_as_float(wb);  // IEEE fp32 mul, RNE
    uint32_t wp = __float_as_uint(p);

    vfloat4 o;
    o.x = (float)((wp >> (sb + 3)) & 1u);
    o.y = (float)((wp >> (sb + 2)) & 1u);
    o.z = (float)((wp >> (sb + 1)) & 1u);
    o.w = (float)((wp >> sb) & 1u);
    __builtin_nontemporal_store(o, &O4[g]);
}

extern "C" void kernel_launch(void* const* d_in, const int* in_sizes, int n_in,
                              void* d_out, int out_size, void* d_ws, size_t ws_size,
                              hipStream_t stream) {
    const vfloat4* A4 = (const vfloat4*)d_in[0];
    const vfloat4* B4 = (const vfloat4*)d_in[1];
    vfloat4* O4 = (vfloat4*)d_out;

    int n4 = in_sizes[0] / 4;   // 16,777,216 float4s; 65536 blocks of 256
    const int block = 256;
    const int grid = (n4 + block - 1) / block;
    spikefp32mul_kernel<<<grid, block, 0, stream>>>(A4, B4, O4, n4);
}